// Round 7
// baseline (394.242 us; speedup 1.0000x reference)
//
#include <hip/hip_runtime.h>

// R7 = CONTROL EXPERIMENT. Six disjoint kernels (R2-R6) all pinned at
// 108-115us (~2.8 TB/s effective, HBM 17%, VALU <19%, no conflicts).
// No model explains it; per rule #10 a ceiling claim needs a known-good
// pattern benched on the same data. This round launches:
//   K2 ctrl_naive   - plain grid-stride float4 read-sum (m13 copy shape)
//   K1 ctrl_pattern - focal's exact addressing+asm pipeline, math stubbed
//   K3 focal_partial- unchanged R6 kernel (baseline + correct output)
// rocprof separates the three dispatches.

typedef float v4f __attribute__((ext_vector_type(4)));

#define B_ROWS 4194304
#define NB 1024           // blocks per task; 4096 waves/task, 32 chunks/wave
#define LOG2E 1.4426950408889634f
#define LN2   0.6931471805599453f

// pair-exchange lane l <-> l^1 via DPP quad_perm [1,0,3,2]
__device__ __forceinline__ float xor1f(float x) {
    int yi = __builtin_amdgcn_update_dpp(0, __builtin_bit_cast(int, x),
                                         0xB1 /*quad_perm(1,0,3,2)*/, 0xF, 0xF, true);
    return __builtin_bit_cast(float, yi);
}

__device__ __forceinline__ void issue_chunk(v4f& q, int& lab,
                                            unsigned voff_log, unsigned voff_lab,
                                            const float* lbase, const int* labase) {
    asm volatile("global_load_dwordx4 %0, %1, %2"
                 : "=&v"(q) : "v"(voff_log), "s"(lbase));
    asm volatile("global_load_dword %0, %1, %2"
                 : "=&v"(lab) : "v"(voff_lab), "s"(labase));
}

#define WAIT_VM(N) do { asm volatile("s_waitcnt vmcnt(" #N ")"); \
                        __builtin_amdgcn_sched_barrier(0); } while (0)

__device__ __forceinline__ float half_row_loss(const v4f q, const int lab,
                                               const int cls_base) {
    const float m4 = fmaxf(fmaxf(q.x, q.y), fmaxf(q.z, q.w));
    const float m  = fmaxf(m4, xor1f(m4));                 // row max over 8
    const float mL = m * LOG2E;
    const float e0 = __builtin_amdgcn_exp2f(__builtin_fmaf(q.x, LOG2E, -mL));
    const float e1 = __builtin_amdgcn_exp2f(__builtin_fmaf(q.y, LOG2E, -mL));
    const float e2 = __builtin_amdgcn_exp2f(__builtin_fmaf(q.z, LOG2E, -mL));
    const float e3 = __builtin_amdgcn_exp2f(__builtin_fmaf(q.w, LOG2E, -mL));
    const float s4 = (e0 + e1) + (e2 + e3);
    const float s  = s4 + xor1f(s4);                       // row denom over 8
    float el4 = 0.0f;
    el4 = (lab == cls_base + 0) ? e0 : el4;
    el4 = (lab == cls_base + 1) ? e1 : el4;
    el4 = (lab == cls_base + 2) ? e2 : el4;
    el4 = (lab == cls_base + 3) ? e3 : el4;
    const float el = el4 + xor1f(el4);                     // e[lab]
    const float pt = el * __builtin_amdgcn_rcpf(s);
    float c = (lab == 0) ? (0.75f * LN2) : (0.25f * LN2);
    c = (lab == 1) ? (0.375f * LN2) : c;
    const float omp = 1.0f - pt;
    const float w = omp * omp;
    const float lg = __builtin_amdgcn_logf(pt + 1e-8f);
    return -(c * w) * lg;
}

// ---------------- K3: real focal kernel (R6, unchanged) ----------------
__global__ __launch_bounds__(256, 8) void focal_partial_kernel(
    const float* __restrict__ logits_dir, const int* __restrict__ labels_dir,
    const float* __restrict__ logits_vol, const int* __restrict__ labels_vol,
    float* __restrict__ partials /* [2][NB] */)
{
    const int task = blockIdx.y;
    const float* __restrict__ logits = task ? logits_vol : logits_dir;
    const int*   __restrict__ labels = task ? labels_vol : labels_dir;

    const int tid = threadIdx.x;
    const int gid = blockIdx.x * 256 + tid;
    const int W = gid >> 6;
    const int l = tid & 63;
    const int cls_base = (l & 1) * 4;
    const unsigned voff_log0 = (unsigned)W * 32768u + (unsigned)l * 16u;
    const unsigned voff_lab0 = (unsigned)W * 4096u  + (unsigned)(l >> 1) * 4u;

    v4f Q[4]; int L[4];
    issue_chunk(Q[0], L[0], voff_log0,          voff_lab0,        logits, labels);
    issue_chunk(Q[1], L[1], voff_log0 + 1024u,  voff_lab0 + 128u, logits, labels);
    issue_chunk(Q[2], L[2], voff_log0 + 2048u,  voff_lab0 + 256u, logits, labels);

    float acc = 0.0f;
    #pragma unroll
    for (int j = 0; j <= 28; ++j) {
        issue_chunk(Q[(j + 3) & 3], L[(j + 3) & 3],
                    voff_log0 + (unsigned)(j + 3) * 1024u,
                    voff_lab0 + (unsigned)(j + 3) * 128u, logits, labels);
        WAIT_VM(6);
        acc += half_row_loss(Q[j & 3], L[j & 3], cls_base);
    }
    WAIT_VM(4); acc += half_row_loss(Q[29 & 3], L[29 & 3], cls_base);
    WAIT_VM(2); acc += half_row_loss(Q[30 & 3], L[30 & 3], cls_base);
    WAIT_VM(0); acc += half_row_loss(Q[31 & 3], L[31 & 3], cls_base);

    #pragma unroll
    for (int off = 32; off > 0; off >>= 1)
        acc += __shfl_down(acc, off);

    __shared__ float lds[4];
    const int lane = threadIdx.x & 63;
    const int wid  = threadIdx.x >> 6;
    if (lane == 0) lds[wid] = acc;
    __syncthreads();
    if (threadIdx.x == 0) {
        const float bsum = (lds[0] + lds[1]) + (lds[2] + lds[3]);
        partials[task * NB + blockIdx.x] = bsum;
    }
}

// ------- K1: identical addressing + pipeline, math stubbed (5 VALU) -------
__global__ __launch_bounds__(256, 8) void ctrl_pattern_kernel(
    const float* __restrict__ logits_dir, const int* __restrict__ labels_dir,
    const float* __restrict__ logits_vol, const int* __restrict__ labels_vol,
    float* __restrict__ ctrl /* [2][NB] */)
{
    const int task = blockIdx.y;
    const float* __restrict__ logits = task ? logits_vol : logits_dir;
    const int*   __restrict__ labels = task ? labels_vol : labels_dir;

    const int tid = threadIdx.x;
    const int gid = blockIdx.x * 256 + tid;
    const int W = gid >> 6;
    const int l = tid & 63;
    const unsigned voff_log0 = (unsigned)W * 32768u + (unsigned)l * 16u;
    const unsigned voff_lab0 = (unsigned)W * 4096u  + (unsigned)(l >> 1) * 4u;

    v4f Q[4]; int L[4];
    issue_chunk(Q[0], L[0], voff_log0,          voff_lab0,        logits, labels);
    issue_chunk(Q[1], L[1], voff_log0 + 1024u,  voff_lab0 + 128u, logits, labels);
    issue_chunk(Q[2], L[2], voff_log0 + 2048u,  voff_lab0 + 256u, logits, labels);

    float acc = 0.0f;
    #pragma unroll
    for (int j = 0; j <= 28; ++j) {
        issue_chunk(Q[(j + 3) & 3], L[(j + 3) & 3],
                    voff_log0 + (unsigned)(j + 3) * 1024u,
                    voff_lab0 + (unsigned)(j + 3) * 128u, logits, labels);
        WAIT_VM(6);
        const v4f q = Q[j & 3];
        acc += (q.x + q.y) + (q.z + q.w) + (float)L[j & 3];   // keep loads live
    }
    { WAIT_VM(4); const v4f q = Q[29 & 3]; acc += (q.x+q.y)+(q.z+q.w) + (float)L[29 & 3]; }
    { WAIT_VM(2); const v4f q = Q[30 & 3]; acc += (q.x+q.y)+(q.z+q.w) + (float)L[30 & 3]; }
    { WAIT_VM(0); const v4f q = Q[31 & 3]; acc += (q.x+q.y)+(q.z+q.w) + (float)L[31 & 3]; }

    #pragma unroll
    for (int off = 32; off > 0; off >>= 1)
        acc += __shfl_down(acc, off);

    __shared__ float lds[4];
    const int lane = threadIdx.x & 63;
    const int wid  = threadIdx.x >> 6;
    if (lane == 0) lds[wid] = acc;
    __syncthreads();
    if (threadIdx.x == 0)
        ctrl[task * NB + blockIdx.x] = (lds[0] + lds[1]) + (lds[2] + lds[3]);
}

// ------- K2: naive plain-HIP grid-stride float4 read-sum (m13 shape) -------
__global__ __launch_bounds__(256) void ctrl_naive_kernel(
    const float4* __restrict__ ld, const float4* __restrict__ lbd,
    const float4* __restrict__ lv, const float4* __restrict__ lbv,
    float* __restrict__ ctrl /* [2048] */)
{
    const int tid = blockIdx.x * 256 + threadIdx.x;
    const int stride = 2048 * 256;
    const int n_log = B_ROWS * 2;   // float4 per logits buffer
    const int n_lab = B_ROWS / 4;   // float4 per labels buffer (bits summed)
    float acc = 0.0f;
    #pragma unroll 4
    for (int i = tid; i < n_log; i += stride) { float4 v = ld[i]; acc += (v.x+v.y)+(v.z+v.w); }
    #pragma unroll 4
    for (int i = tid; i < n_log; i += stride) { float4 v = lv[i]; acc += (v.x+v.y)+(v.z+v.w); }
    #pragma unroll 4
    for (int i = tid; i < n_lab; i += stride) { float4 v = lbd[i]; acc += (v.x+v.y)+(v.z+v.w); }
    #pragma unroll 4
    for (int i = tid; i < n_lab; i += stride) { float4 v = lbv[i]; acc += (v.x+v.y)+(v.z+v.w); }

    #pragma unroll
    for (int off = 32; off > 0; off >>= 1)
        acc += __shfl_down(acc, off);

    __shared__ float lds[4];
    const int lane = threadIdx.x & 63;
    const int wid  = threadIdx.x >> 6;
    if (lane == 0) lds[wid] = acc;
    __syncthreads();
    if (threadIdx.x == 0)
        ctrl[blockIdx.x] = (lds[0] + lds[1]) + (lds[2] + lds[3]);
}

__global__ __launch_bounds__(256) void focal_final_kernel(
    const float* __restrict__ partials, float* __restrict__ out)
{
    double sd = 0.0, sv = 0.0;
    for (int k = threadIdx.x; k < NB; k += 256) {
        sd += (double)partials[k];
        sv += (double)partials[NB + k];
    }
    #pragma unroll
    for (int off = 32; off > 0; off >>= 1) {
        sd += __shfl_down(sd, off);
        sv += __shfl_down(sv, off);
    }
    __shared__ double lds[8];
    const int lane = threadIdx.x & 63;
    const int wid  = threadIdx.x >> 6;
    if (lane == 0) { lds[wid] = sd; lds[4 + wid] = sv; }
    __syncthreads();
    if (threadIdx.x == 0) {
        // each row accumulated by BOTH lanes of its pair -> divide by 2B
        const double l_dir = ((lds[0] + lds[1]) + (lds[2] + lds[3])) / (2.0 * (double)B_ROWS);
        const double l_vol = ((lds[4] + lds[5]) + (lds[6] + lds[7])) / (2.0 * (double)B_ROWS);
        out[0] = (float)(l_dir + 0.5 * l_vol);
        out[1] = (float)l_dir;
        out[2] = (float)l_vol;
    }
}

extern "C" void kernel_launch(void* const* d_in, const int* in_sizes, int n_in,
                              void* d_out, int out_size, void* d_ws, size_t ws_size,
                              hipStream_t stream) {
    const float* logits_dir = (const float*)d_in[0];
    const int*   labels_dir = (const int*)d_in[1];
    const float* logits_vol = (const float*)d_in[2];
    const int*   labels_vol = (const int*)d_in[3];
    float* out = (float*)d_out;
    float* partials = (float*)d_ws;            // [2*NB]
    float* k1ctrl   = partials + 2 * NB;       // [2*NB]   (ignored by finisher)
    float* k2ctrl   = partials + 4 * NB;       // [2048]   (ignored by finisher)

    // K2: naive known-good stream (platform ceiling probe)
    ctrl_naive_kernel<<<2048, 256, 0, stream>>>(
        (const float4*)logits_dir, (const float4*)labels_dir,
        (const float4*)logits_vol, (const float4*)labels_vol, k2ctrl);
    // K1: focal addressing/pipeline, math stubbed (structure probe)
    dim3 grid(NB, 2);
    ctrl_pattern_kernel<<<grid, 256, 0, stream>>>(logits_dir, labels_dir,
                                                  logits_vol, labels_vol, k1ctrl);
    // K3: real kernel (unchanged R6) + finisher
    focal_partial_kernel<<<grid, 256, 0, stream>>>(logits_dir, labels_dir,
                                                   logits_vol, labels_vol, partials);
    focal_final_kernel<<<1, 256, 0, stream>>>(partials, out);
}

// Round 10
// 272.127 us; speedup vs baseline: 1.4487x; 1.4487x over previous
//
#include <hip/hip_runtime.h>

// Focal multi-task loss, B=4194304 rows, C=8 classes, two tasks.
// R7 control: naive dense float4 read-sum == focal kernel == 115us, and a
// READ-ONLY kernel shows WRITE_SIZE=68MB -> harness's input-restore leaves
// L3 dirty; 302MB footprint > 256MB L3 -> allocate-on-read thrash + dirty
// writebacks serialize with fetches. R8: NON-TEMPORAL loads (no L3
// allocation -> no evictions -> no writebacks, pure HBM read stream).
// Scheduling proven irrelevant (R5/R6/R7) -> plain compiler-scheduled code.
// (R8+R9 benches lost to GPU-capacity timeouts; identical resubmit.)

typedef float v4f __attribute__((ext_vector_type(4)));

#define B_ROWS 4194304
#define NB 1024           // blocks per task; 4096 waves/task, 32 chunks/wave
#define LOG2E 1.4426950408889634f
#define LN2   0.6931471805599453f

// pair-exchange lane l <-> l^1 via DPP quad_perm [1,0,3,2] (pure VALU)
__device__ __forceinline__ float xor1f(float x) {
    int yi = __builtin_amdgcn_update_dpp(0, __builtin_bit_cast(int, x),
                                         0xB1 /*quad_perm(1,0,3,2)*/, 0xF, 0xF, true);
    return __builtin_bit_cast(float, yi);
}

// Lane holds classes [cls_base, cls_base+4) of its row; partner has the rest.
// All pair-combines commutative -> bit-identical result in both lanes.
__device__ __forceinline__ float half_row_loss(const v4f q, const int lab,
                                               const int cls_base) {
    const float m4 = fmaxf(fmaxf(q.x, q.y), fmaxf(q.z, q.w));
    const float m  = fmaxf(m4, xor1f(m4));                 // row max over 8
    const float mL = m * LOG2E;
    const float e0 = __builtin_amdgcn_exp2f(__builtin_fmaf(q.x, LOG2E, -mL));
    const float e1 = __builtin_amdgcn_exp2f(__builtin_fmaf(q.y, LOG2E, -mL));
    const float e2 = __builtin_amdgcn_exp2f(__builtin_fmaf(q.z, LOG2E, -mL));
    const float e3 = __builtin_amdgcn_exp2f(__builtin_fmaf(q.w, LOG2E, -mL));
    const float s4 = (e0 + e1) + (e2 + e3);
    const float s  = s4 + xor1f(s4);                       // row denom over 8
    float el4 = 0.0f;                                      // e[lab] if mine else 0
    el4 = (lab == cls_base + 0) ? e0 : el4;
    el4 = (lab == cls_base + 1) ? e1 : el4;
    el4 = (lab == cls_base + 2) ? e2 : el4;
    el4 = (lab == cls_base + 3) ? e3 : el4;
    const float el = el4 + xor1f(el4);                     // e[lab]
    const float pt = el * __builtin_amdgcn_rcpf(s);
    float c = (lab == 0) ? (0.75f * LN2) : (0.25f * LN2);  // alpha_t*boost*ln2
    c = (lab == 1) ? (0.375f * LN2) : c;
    const float omp = 1.0f - pt;
    const float w = omp * omp;                             // (1-pt)^2
    const float lg = __builtin_amdgcn_logf(pt + 1e-8f);    // log2(pt+1e-8)
    return -(c * w) * lg;
}

__global__ __launch_bounds__(256, 8) void focal_partial_kernel(
    const float* __restrict__ logits_dir, const int* __restrict__ labels_dir,
    const float* __restrict__ logits_vol, const int* __restrict__ labels_vol,
    float* __restrict__ partials /* [2][NB] */)
{
    const int task = blockIdx.y;
    const float* __restrict__ logits = task ? logits_vol : logits_dir;
    const int*   __restrict__ labels = task ? labels_vol : labels_dir;

    const int tid = threadIdx.x;
    const int gid = blockIdx.x * 256 + tid;
    const int W = gid >> 6;                 // global wave id, 0..4095 per task
    const int l = tid & 63;
    const int cls_base = (l & 1) * 4;
    // wave W owns 32 consecutive 1KB chunks (32 rows each): 32KB contiguous.
    // Lane l reads the float4 at chunk-offset l*16B -> fully dense wave access.
    const v4f* __restrict__ logbase = (const v4f*)logits + (size_t)W * 2048 + l;
    const int* __restrict__ labbase = labels + (size_t)W * 1024 + (l >> 1);

    float acc = 0.0f;
    #pragma unroll 4
    for (int j = 0; j < 32; ++j) {
        // NON-TEMPORAL: no L2/L3 allocation -> no dirty-line evictions
        const v4f q  = __builtin_nontemporal_load(logbase + j * 64);
        const int lab = __builtin_nontemporal_load(labbase + j * 32);
        acc += half_row_loss(q, lab, cls_base);
    }

    // wave reduce (each row counted twice -> finisher divides by 2B)
    #pragma unroll
    for (int off = 32; off > 0; off >>= 1)
        acc += __shfl_down(acc, off);

    __shared__ float lds[4];
    const int lane = threadIdx.x & 63;
    const int wid  = threadIdx.x >> 6;
    if (lane == 0) lds[wid] = acc;
    __syncthreads();
    if (threadIdx.x == 0) {
        const float bsum = (lds[0] + lds[1]) + (lds[2] + lds[3]);
        partials[task * NB + blockIdx.x] = bsum;
    }
}

__global__ __launch_bounds__(256) void focal_final_kernel(
    const float* __restrict__ partials, float* __restrict__ out)
{
    double sd = 0.0, sv = 0.0;
    for (int k = threadIdx.x; k < NB; k += 256) {
        sd += (double)partials[k];
        sv += (double)partials[NB + k];
    }
    #pragma unroll
    for (int off = 32; off > 0; off >>= 1) {
        sd += __shfl_down(sd, off);
        sv += __shfl_down(sv, off);
    }
    __shared__ double lds[8];
    const int lane = threadIdx.x & 63;
    const int wid  = threadIdx.x >> 6;
    if (lane == 0) { lds[wid] = sd; lds[4 + wid] = sv; }
    __syncthreads();
    if (threadIdx.x == 0) {
        // each row accumulated by BOTH lanes of its pair -> divide by 2B
        const double l_dir = ((lds[0] + lds[1]) + (lds[2] + lds[3])) / (2.0 * (double)B_ROWS);
        const double l_vol = ((lds[4] + lds[5]) + (lds[6] + lds[7])) / (2.0 * (double)B_ROWS);
        out[0] = (float)(l_dir + 0.5 * l_vol);  // total = 1.0*dir + 0.5*vol
        out[1] = (float)l_dir;
        out[2] = (float)l_vol;
    }
}

extern "C" void kernel_launch(void* const* d_in, const int* in_sizes, int n_in,
                              void* d_out, int out_size, void* d_ws, size_t ws_size,
                              hipStream_t stream) {
    const float* logits_dir = (const float*)d_in[0];
    const int*   labels_dir = (const int*)d_in[1];
    const float* logits_vol = (const float*)d_in[2];
    const int*   labels_vol = (const int*)d_in[3];
    float* out = (float*)d_out;
    float* partials = (float*)d_ws;  // 2*NB floats = 8 KB, fully overwritten each call

    dim3 grid(NB, 2);
    focal_partial_kernel<<<grid, 256, 0, stream>>>(logits_dir, labels_dir,
                                                   logits_vol, labels_vol, partials);
    focal_final_kernel<<<1, 256, 0, stream>>>(partials, out);
}